// Round 10
// baseline (1615.308 us; speedup 1.0000x reference)
//
#include <hip/hip_runtime.h>
#include <hip/hip_bf16.h>

// GRU-D fused scan, MFMA broadcast-B edition v2 (register diet).
// R9 passed (all MFMA layouts verified) but spilled: weights 168 + biases 32
// + temps ~65 = ~264 regs > 256/wave budget -> 72 MB scratch WRITE_SIZE,
// loop reloads from L2, VALUBusy 56%. v2 shaves ~35 permanently-live regs:
//   1. biases -> LDS (8 planes x 128 f32); per-step fx4 C-init loads.
//   2. (mask,dt) K-chunk: hx widened to 64 f16; A-side wih0c1f frags are
//      loop-invariant (R9 rebuilt 24 zeros per step).
//   3. h0 B-frags reloaded per use instead of cached across layers (-16 regs).
// Peak ~230 < 256 -> no spill. Everything else identical to R9:
// wave w owns 16-unit tile for BOTH layers, B columns all = h (D replicates),
// h_old in regs, double-buffered LDS state, ONE barrier/step, L1 staggered.

#define BB 256
#define SS 1024
#define DD 32
#define HH 128
#define NT 512

typedef _Float16 f16;
typedef __attribute__((ext_vector_type(2))) _Float16 h2;
typedef __attribute__((ext_vector_type(8))) _Float16 h8;   // MFMA A/B frag
typedef __attribute__((ext_vector_type(4))) float fx4;     // MFMA C/D frag

__device__ inline fx4 mfma(h8 a, h8 b, fx4 c) {
    return __builtin_amdgcn_mfma_f32_16x16x32_f16(a, b, c, 0, 0, 0);
}

__device__ inline float frcp(float x) { return __builtin_amdgcn_rcpf(x); }
__device__ inline float fast_sigm(float x) { return frcp(1.0f + __expf(-x)); }
__device__ inline float fast_tanh(float x) {
    x = fminf(15.0f, fmaxf(-15.0f, x));
    float e = __expf(-2.0f * x);
    return (1.0f - e) * frcp(1.0f + e);
}

struct ImpState { float xprev, tprev; bool hasprev; };

// Wave 0 only (all 64 lanes active; lane l<32 owns feature l). hxd is a
// 64-f16 buffer: [0..31] features, [32] mask, [33] texp, [34..63] zero (init).
__device__ inline void impute_store(int i, float xv, int lane, ImpState& st,
                                    f16* hxd, const float* tb) {
    bool nanp = (lane < 32) && (xv != xv);
    unsigned long long bal = __ballot(nanp);
    bool mask = bal != 0ull;
    if (lane < 32) {
        float imp = mask ? st.xprev : xv;
        hxd[lane] = (f16)imp;
        if (!mask) st.xprev = xv;
    }
    float tcur = tb[i];
    float tdel = (i == 0) ? 0.0f : (tcur - tb[i - 1]);
    float texp = st.hasprev ? (tcur - st.tprev) : tdel;
    if (lane == 32) hxd[32] = (f16)(mask ? 1.0f : 0.0f);
    if (lane == 33) hxd[33] = (f16)texp;
    if (!mask) { st.hasprev = true; st.tprev = tcur; }
}

__global__ __launch_bounds__(NT, 2) void gru_fused(
    const float* __restrict__ t_in, const float* __restrict__ x_in,
    const float* __restrict__ Wih0, const float* __restrict__ Whh0,
    const float* __restrict__ bih0, const float* __restrict__ bhh0,
    const float* __restrict__ Wih1, const float* __restrict__ Whh1,
    const float* __restrict__ bih1, const float* __restrict__ bhh1,
    float* __restrict__ out)
{
    __shared__ float tb[SS];                       // timestamps (4 KB)
    __shared__ alignas(16) float blds[1024];       // biases: 8 planes x 128 (4 KB)
    __shared__ alignas(16) f16 h0s[2][HH];         // h0 state, double-buffered
    __shared__ alignas(16) f16 h1s[2][HH];         // h1 state
    __shared__ alignas(16) f16 hxs[2][64];         // imputed input (K=64 padded)

    const int tid = threadIdx.x;
    const int lane = tid & 63;
    const int w = tid >> 6;        // wave id = unit-tile (16 units: 16w..16w+15)
    const int q = lane >> 4;       // quad (K-group / D-row-group)
    const int m = lane & 15;       // A row within tile / D col
    const int r4 = 16 * w + 4 * q; // D rows 4q..4q+3 of this tile
    const int b = blockIdx.x;

    // ---- A-fragments (weights f32 -> f16), rows = gate g, units 16w+m ----
    // frag element j <-> k = 32c + 8q + j
    h8 whh0f[3][4], wih1f[3][4], whh1f[3][4], wih0c0[3], wih0c1f[3];
    #pragma unroll
    for (int g = 0; g < 3; g++) {
        const int row = 128 * g + 16 * w + m;
        const float* pa = Whh0 + (size_t)row * HH;
        const float* pb = Wih1 + (size_t)row * HH;
        const float* pc = Whh1 + (size_t)row * HH;
        const float* pd = Wih0 + (size_t)row * 34;
        #pragma unroll
        for (int c = 0; c < 4; c++) {
            h8 va, vb, vc;
            #pragma unroll
            for (int j = 0; j < 8; j++) {
                int k = 32 * c + 8 * q + j;
                va[j] = (f16)pa[k]; vb[j] = (f16)pb[k]; vc[j] = (f16)pc[k];
            }
            whh0f[g][c] = va; wih1f[g][c] = vb; whh1f[g][c] = vc;
        }
        h8 vd, ve;
        #pragma unroll
        for (int j = 0; j < 8; j++) { vd[j] = (f16)pd[8 * q + j]; ve[j] = (f16)0.0f; }
        wih0c0[g] = vd;
        ve[0] = (q == 0) ? (f16)pd[32] : (f16)0.0f;   // k=32: mask col
        ve[1] = (q == 0) ? (f16)pd[33] : (f16)0.0f;   // k=33: texp col
        wih0c1f[g] = ve;
    }

    // ---- biases -> LDS planes: 0 bR0 1 bZ0 2 bNi0 3 bNh0, 4-7 layer 1 ----
    for (int idx = tid; idx < 1024; idx += NT) {
        int pl = idx >> 7, j = idx & 127, pp = pl & 3;
        const float* bi = (pl < 4) ? bih0 : bih1;
        const float* bh = (pl < 4) ? bhh0 : bhh1;
        float v;
        if (pp == 0)      v = bi[j] + bh[j];
        else if (pp == 1) v = bi[128 + j] + bh[128 + j];
        else if (pp == 2) v = bi[256 + j];
        else              v = bh[256 + j];
        blds[idx] = v;
    }

    // ---- prologue: tb, zero state slots (both), impute step 0 ----
    for (int i2 = tid; i2 < SS; i2 += NT) tb[i2] = t_in[i2];
    if (tid < 128)      ((int*)h0s)[tid] = 0;
    else if (tid < 256) ((int*)h1s)[tid - 128] = 0;
    else if (tid < 320) ((int*)hxs)[tid - 256] = 0;

    const float* xrow = x_in + (size_t)b * SS * DD + lane;  // deref lanes<32, wave0
    ImpState st; st.xprev = 0.0f; st.tprev = 0.0f; st.hasprev = false;
    fx4 hn0 = {0.f, 0.f, 0.f, 0.f}, hn1 = {0.f, 0.f, 0.f, 0.f};

    __syncthreads();
    if (w == 0) {
        float xv0 = (lane < 32) ? xrow[0] : 0.0f;
        impute_store(0, xv0, lane, st, hxs[0], tb);
    }
    __syncthreads();

    for (int i = 0; i <= SS; ++i) {
        const int p = i & 1, np = p ^ 1;
        const bool doL0 = (i < SS), doL1 = (i > 0), doImp = (i + 1 < SS);

        float xnext = 0.0f;
        if (w == 0 && lane < 32 && doImp) xnext = xrow[(size_t)(i + 1) * DD];

        const f16* h0p = h0s[p];

        // ---- layer 0: step i ----
        if (doL0) {
            fx4 r  = *(const fx4*)&blds[r4];
            fx4 z  = *(const fx4*)&blds[128 + r4];
            fx4 ni = *(const fx4*)&blds[256 + r4];
            fx4 nh = *(const fx4*)&blds[384 + r4];
            h8 bx0 = *(const h8*)(hxs[p] + 8 * q);
            h8 bx1 = *(const h8*)(hxs[p] + 32 + 8 * q);
            r  = mfma(wih0c0[0], bx0, r);
            z  = mfma(wih0c0[1], bx0, z);
            ni = mfma(wih0c0[2], bx0, ni);
            r  = mfma(wih0c1f[0], bx1, r);
            z  = mfma(wih0c1f[1], bx1, z);
            ni = mfma(wih0c1f[2], bx1, ni);
            #pragma unroll
            for (int c = 0; c < 4; c++) {
                h8 bc = *(const h8*)(h0p + 32 * c + 8 * q);
                r  = mfma(whh0f[0][c], bc, r);
                z  = mfma(whh0f[1][c], bc, z);
                nh = mfma(whh0f[2][c], bc, nh);
            }
            #pragma unroll
            for (int e = 0; e < 4; e++) {
                float rr = fast_sigm(r[e]);
                float zz = fast_sigm(z[e]);
                float nn = fast_tanh(ni[e] + rr * nh[e]);
                hn0[e] = (1.0f - zz) * nn + zz * hn0[e];
            }
            if (m == 0) {   // publish rows 4q..4q+3 of tile w to next slot
                h2 lo; lo.x = (f16)hn0[0]; lo.y = (f16)hn0[1];
                h2 hi; hi.x = (f16)hn0[2]; hi.y = (f16)hn0[3];
                h2* dst = (h2*)(h0s[np] + r4);
                dst[0] = lo; dst[1] = hi;
            }
        }

        // ---- layer 1: step i-1 ----
        if (doL1) {
            fx4 r1  = *(const fx4*)&blds[512 + r4];
            fx4 z1  = *(const fx4*)&blds[640 + r4];
            fx4 ni1 = *(const fx4*)&blds[768 + r4];
            fx4 nh1 = *(const fx4*)&blds[896 + r4];
            #pragma unroll
            for (int c = 0; c < 4; c++) {
                h8 bc = *(const h8*)(h0p + 32 * c + 8 * q);
                r1  = mfma(wih1f[0][c], bc, r1);
                z1  = mfma(wih1f[1][c], bc, z1);
                ni1 = mfma(wih1f[2][c], bc, ni1);
            }
            const f16* h1p = h1s[p];
            #pragma unroll
            for (int c = 0; c < 4; c++) {
                h8 bc = *(const h8*)(h1p + 32 * c + 8 * q);
                r1  = mfma(whh1f[0][c], bc, r1);
                z1  = mfma(whh1f[1][c], bc, z1);
                nh1 = mfma(whh1f[2][c], bc, nh1);
            }
            #pragma unroll
            for (int e = 0; e < 4; e++) {
                float rr = fast_sigm(r1[e]);
                float zz = fast_sigm(z1[e]);
                float nn = fast_tanh(ni1[e] + rr * nh1[e]);
                hn1[e] = (1.0f - zz) * nn + zz * hn1[e];
            }
            if (m == 0) {
                h2 lo; lo.x = (f16)hn1[0]; lo.y = (f16)hn1[1];
                h2 hi; hi.x = (f16)hn1[2]; hi.y = (f16)hn1[3];
                h2* dst = (h2*)(h1s[np] + r4);
                dst[0] = lo; dst[1] = hi;
            }
        }

        // ---- imputation for step i+1 (wave 0) ----
        if (w == 0 && doImp)
            impute_store(i + 1, xnext, lane, st, hxs[np], tb);

        __syncthreads();   // single barrier: slot-np publishes visible;
                           // slot-p reads all happened pre-barrier
    }

    if (m == 0) {   // lane (q, m=0) holds final h1 for units 16w+4q..+3
        *(fx4*)(out + (size_t)b * HH + r4) = hn1;
    }
}

extern "C" void kernel_launch(void* const* d_in, const int* in_sizes, int n_in,
                              void* d_out, int out_size, void* d_ws, size_t ws_size,
                              hipStream_t stream) {
    gru_fused<<<dim3(BB), dim3(NT), 0, stream>>>(
        (const float*)d_in[0], (const float*)d_in[1],
        (const float*)d_in[2], (const float*)d_in[3],
        (const float*)d_in[4], (const float*)d_in[5],
        (const float*)d_in[6], (const float*)d_in[7],
        (const float*)d_in[8], (const float*)d_in[9],
        (float*)d_out);
}

// Round 11
// 1612.786 us; speedup vs baseline: 1.0016x; 1.0016x over previous
//
#include <hip/hip_runtime.h>
#include <hip/hip_bf16.h>

// GRU-D fused scan, MFMA broadcast-B edition v3 (launch-bounds fix).
// SESSION-WIDE DIAGNOSIS (R10 post-mortem): __launch_bounds__(NT, k) made the
// compiler allocate registers for 2k waves/SIMD — twice what our 1-block/CU
// launch ever runs (R2..R7: (768,3) -> VGPR_Count 84 = 512/6; R9/R10:
// (512,2) -> 128 = 512/4). Every kernel ran with HALF its usable registers;
// the overflow became AGPR copies + scratch spill (WRITE_SIZE 45-72 MB) and
// the persistent ~2x VALU inflation. Fix: plain __launch_bounds__(512) — the
// allocator sizes to actual demand (~244 <= 256 at our real 2 waves/SIMD).
// Kernel body is byte-identical to R10 (single-variable experiment):
// wave w owns 16-unit tile for BOTH layers, B columns all = h (D replicates),
// A-frags resident, biases in LDS, h_old in regs, double-buffered LDS state,
// ONE barrier/step, L1 staggered one step behind L0.

#define BB 256
#define SS 1024
#define DD 32
#define HH 128
#define NT 512

typedef _Float16 f16;
typedef __attribute__((ext_vector_type(2))) _Float16 h2;
typedef __attribute__((ext_vector_type(8))) _Float16 h8;   // MFMA A/B frag
typedef __attribute__((ext_vector_type(4))) float fx4;     // MFMA C/D frag

__device__ inline fx4 mfma(h8 a, h8 b, fx4 c) {
    return __builtin_amdgcn_mfma_f32_16x16x32_f16(a, b, c, 0, 0, 0);
}

__device__ inline float frcp(float x) { return __builtin_amdgcn_rcpf(x); }
__device__ inline float fast_sigm(float x) { return frcp(1.0f + __expf(-x)); }
__device__ inline float fast_tanh(float x) {
    x = fminf(15.0f, fmaxf(-15.0f, x));
    float e = __expf(-2.0f * x);
    return (1.0f - e) * frcp(1.0f + e);
}

struct ImpState { float xprev, tprev; bool hasprev; };

// Wave 0 only (all 64 lanes active; lane l<32 owns feature l). hxd is a
// 64-f16 buffer: [0..31] features, [32] mask, [33] texp, [34..63] zero (init).
__device__ inline void impute_store(int i, float xv, int lane, ImpState& st,
                                    f16* hxd, const float* tb) {
    bool nanp = (lane < 32) && (xv != xv);
    unsigned long long bal = __ballot(nanp);
    bool mask = bal != 0ull;
    if (lane < 32) {
        float imp = mask ? st.xprev : xv;
        hxd[lane] = (f16)imp;
        if (!mask) st.xprev = xv;
    }
    float tcur = tb[i];
    float tdel = (i == 0) ? 0.0f : (tcur - tb[i - 1]);
    float texp = st.hasprev ? (tcur - st.tprev) : tdel;
    if (lane == 32) hxd[32] = (f16)(mask ? 1.0f : 0.0f);
    if (lane == 33) hxd[33] = (f16)texp;
    if (!mask) { st.hasprev = true; st.tprev = tcur; }
}

__global__ __launch_bounds__(NT) void gru_fused(
    const float* __restrict__ t_in, const float* __restrict__ x_in,
    const float* __restrict__ Wih0, const float* __restrict__ Whh0,
    const float* __restrict__ bih0, const float* __restrict__ bhh0,
    const float* __restrict__ Wih1, const float* __restrict__ Whh1,
    const float* __restrict__ bih1, const float* __restrict__ bhh1,
    float* __restrict__ out)
{
    __shared__ float tb[SS];                       // timestamps (4 KB)
    __shared__ alignas(16) float blds[1024];       // biases: 8 planes x 128 (4 KB)
    __shared__ alignas(16) f16 h0s[2][HH];         // h0 state, double-buffered
    __shared__ alignas(16) f16 h1s[2][HH];         // h1 state
    __shared__ alignas(16) f16 hxs[2][64];         // imputed input (K=64 padded)

    const int tid = threadIdx.x;
    const int lane = tid & 63;
    const int w = tid >> 6;        // wave id = unit-tile (16 units: 16w..16w+15)
    const int q = lane >> 4;       // quad (K-group / D-row-group)
    const int m = lane & 15;       // A row within tile / D col
    const int r4 = 16 * w + 4 * q; // D rows 4q..4q+3 of this tile
    const int b = blockIdx.x;

    // ---- A-fragments (weights f32 -> f16), rows = gate g, units 16w+m ----
    // frag element j <-> k = 32c + 8q + j
    h8 whh0f[3][4], wih1f[3][4], whh1f[3][4], wih0c0[3], wih0c1f[3];
    #pragma unroll
    for (int g = 0; g < 3; g++) {
        const int row = 128 * g + 16 * w + m;
        const float* pa = Whh0 + (size_t)row * HH;
        const float* pb = Wih1 + (size_t)row * HH;
        const float* pc = Whh1 + (size_t)row * HH;
        const float* pd = Wih0 + (size_t)row * 34;
        #pragma unroll
        for (int c = 0; c < 4; c++) {
            h8 va, vb, vc;
            #pragma unroll
            for (int j = 0; j < 8; j++) {
                int k = 32 * c + 8 * q + j;
                va[j] = (f16)pa[k]; vb[j] = (f16)pb[k]; vc[j] = (f16)pc[k];
            }
            whh0f[g][c] = va; wih1f[g][c] = vb; whh1f[g][c] = vc;
        }
        h8 vd, ve;
        #pragma unroll
        for (int j = 0; j < 8; j++) { vd[j] = (f16)pd[8 * q + j]; ve[j] = (f16)0.0f; }
        wih0c0[g] = vd;
        ve[0] = (q == 0) ? (f16)pd[32] : (f16)0.0f;   // k=32: mask col
        ve[1] = (q == 0) ? (f16)pd[33] : (f16)0.0f;   // k=33: texp col
        wih0c1f[g] = ve;
    }

    // ---- biases -> LDS planes: 0 bR0 1 bZ0 2 bNi0 3 bNh0, 4-7 layer 1 ----
    for (int idx = tid; idx < 1024; idx += NT) {
        int pl = idx >> 7, j = idx & 127, pp = pl & 3;
        const float* bi = (pl < 4) ? bih0 : bih1;
        const float* bh = (pl < 4) ? bhh0 : bhh1;
        float v;
        if (pp == 0)      v = bi[j] + bh[j];
        else if (pp == 1) v = bi[128 + j] + bh[128 + j];
        else if (pp == 2) v = bi[256 + j];
        else              v = bh[256 + j];
        blds[idx] = v;
    }

    // ---- prologue: tb, zero state slots (both), impute step 0 ----
    for (int i2 = tid; i2 < SS; i2 += NT) tb[i2] = t_in[i2];
    if (tid < 128)      ((int*)h0s)[tid] = 0;
    else if (tid < 256) ((int*)h1s)[tid - 128] = 0;
    else if (tid < 320) ((int*)hxs)[tid - 256] = 0;

    const float* xrow = x_in + (size_t)b * SS * DD + lane;  // deref lanes<32, wave0
    ImpState st; st.xprev = 0.0f; st.tprev = 0.0f; st.hasprev = false;
    fx4 hn0 = {0.f, 0.f, 0.f, 0.f}, hn1 = {0.f, 0.f, 0.f, 0.f};

    __syncthreads();
    if (w == 0) {
        float xv0 = (lane < 32) ? xrow[0] : 0.0f;
        impute_store(0, xv0, lane, st, hxs[0], tb);
    }
    __syncthreads();

    for (int i = 0; i <= SS; ++i) {
        const int p = i & 1, np = p ^ 1;
        const bool doL0 = (i < SS), doL1 = (i > 0), doImp = (i + 1 < SS);

        float xnext = 0.0f;
        if (w == 0 && lane < 32 && doImp) xnext = xrow[(size_t)(i + 1) * DD];

        const f16* h0p = h0s[p];

        // ---- layer 0: step i ----
        if (doL0) {
            fx4 r  = *(const fx4*)&blds[r4];
            fx4 z  = *(const fx4*)&blds[128 + r4];
            fx4 ni = *(const fx4*)&blds[256 + r4];
            fx4 nh = *(const fx4*)&blds[384 + r4];
            h8 bx0 = *(const h8*)(hxs[p] + 8 * q);
            h8 bx1 = *(const h8*)(hxs[p] + 32 + 8 * q);
            r  = mfma(wih0c0[0], bx0, r);
            z  = mfma(wih0c0[1], bx0, z);
            ni = mfma(wih0c0[2], bx0, ni);
            r  = mfma(wih0c1f[0], bx1, r);
            z  = mfma(wih0c1f[1], bx1, z);
            ni = mfma(wih0c1f[2], bx1, ni);
            #pragma unroll
            for (int c = 0; c < 4; c++) {
                h8 bc = *(const h8*)(h0p + 32 * c + 8 * q);
                r  = mfma(whh0f[0][c], bc, r);
                z  = mfma(whh0f[1][c], bc, z);
                nh = mfma(whh0f[2][c], bc, nh);
            }
            #pragma unroll
            for (int e = 0; e < 4; e++) {
                float rr = fast_sigm(r[e]);
                float zz = fast_sigm(z[e]);
                float nn = fast_tanh(ni[e] + rr * nh[e]);
                hn0[e] = (1.0f - zz) * nn + zz * hn0[e];
            }
            if (m == 0) {   // publish rows 4q..4q+3 of tile w to next slot
                h2 lo; lo.x = (f16)hn0[0]; lo.y = (f16)hn0[1];
                h2 hi; hi.x = (f16)hn0[2]; hi.y = (f16)hn0[3];
                h2* dst = (h2*)(h0s[np] + r4);
                dst[0] = lo; dst[1] = hi;
            }
        }

        // ---- layer 1: step i-1 ----
        if (doL1) {
            fx4 r1  = *(const fx4*)&blds[512 + r4];
            fx4 z1  = *(const fx4*)&blds[640 + r4];
            fx4 ni1 = *(const fx4*)&blds[768 + r4];
            fx4 nh1 = *(const fx4*)&blds[896 + r4];
            #pragma unroll
            for (int c = 0; c < 4; c++) {
                h8 bc = *(const h8*)(h0p + 32 * c + 8 * q);
                r1  = mfma(wih1f[0][c], bc, r1);
                z1  = mfma(wih1f[1][c], bc, z1);
                ni1 = mfma(wih1f[2][c], bc, ni1);
            }
            const f16* h1p = h1s[p];
            #pragma unroll
            for (int c = 0; c < 4; c++) {
                h8 bc = *(const h8*)(h1p + 32 * c + 8 * q);
                r1  = mfma(whh1f[0][c], bc, r1);
                z1  = mfma(whh1f[1][c], bc, z1);
                nh1 = mfma(whh1f[2][c], bc, nh1);
            }
            #pragma unroll
            for (int e = 0; e < 4; e++) {
                float rr = fast_sigm(r1[e]);
                float zz = fast_sigm(z1[e]);
                float nn = fast_tanh(ni1[e] + rr * nh1[e]);
                hn1[e] = (1.0f - zz) * nn + zz * hn1[e];
            }
            if (m == 0) {
                h2 lo; lo.x = (f16)hn1[0]; lo.y = (f16)hn1[1];
                h2 hi; hi.x = (f16)hn1[2]; hi.y = (f16)hn1[3];
                h2* dst = (h2*)(h1s[np] + r4);
                dst[0] = lo; dst[1] = hi;
            }
        }

        // ---- imputation for step i+1 (wave 0) ----
        if (w == 0 && doImp)
            impute_store(i + 1, xnext, lane, st, hxs[np], tb);

        __syncthreads();   // single barrier: slot-np publishes visible;
                           // slot-p reads all happened pre-barrier
    }

    if (m == 0) {   // lane (q, m=0) holds final h1 for units 16w+4q..+3
        *(fx4*)(out + (size_t)b * HH + r4) = hn1;
    }
}

extern "C" void kernel_launch(void* const* d_in, const int* in_sizes, int n_in,
                              void* d_out, int out_size, void* d_ws, size_t ws_size,
                              hipStream_t stream) {
    gru_fused<<<dim3(BB), dim3(NT), 0, stream>>>(
        (const float*)d_in[0], (const float*)d_in[1],
        (const float*)d_in[2], (const float*)d_in[3],
        (const float*)d_in[4], (const float*)d_in[5],
        (const float*)d_in[6], (const float*)d_in[7],
        (const float*)d_in[8], (const float*)d_in[9],
        (float*)d_out);
}